// Round 2
// baseline (1594.573 us; speedup 1.0000x reference)
//
#include <hip/hip_runtime.h>

// ---------------------------------------------------------------------------
// Problem constants
// ---------------------------------------------------------------------------
#define NUSER 50000
#define NITEM 50000
#define NEDGE 100000
#define HDIM  512      // H*D
#define KIN   256      // input feature dim

typedef unsigned short ushort_t;
typedef __attribute__((ext_vector_type(8))) short short8;
typedef __attribute__((ext_vector_type(4))) float f32x4;

static __device__ __forceinline__ float bf2f(ushort_t u) {
    unsigned v = ((unsigned)u) << 16;
    float f;
    __builtin_memcpy(&f, &v, 4);
    return f;
}
static __device__ __forceinline__ ushort_t f2bf(float f) {
    unsigned u;
    __builtin_memcpy(&u, &f, 4);
    unsigned r = u + 0x7fffu + ((u >> 16) & 1u);  // RNE
    return (ushort_t)(r >> 16);
}
// runtime-dtype scalar load
static __device__ __forceinline__ float ldf(const void* p, long i, bool fp32) {
    return fp32 ? ((const float*)p)[i] : bf2f(((const ushort_t*)p)[i]);
}

#define GLOBAL_AS __attribute__((address_space(1)))
#define LDS_AS    __attribute__((address_space(3)))
static __device__ __forceinline__ void load_lds16(const void* g, void* l) {
    __builtin_amdgcn_global_load_lds((const GLOBAL_AS void*)g, (LDS_AS void*)l, 16, 0, 0);
}

// ---------------------------------------------------------------------------
// D0: runtime dtype detection. If the float tensors are fp32 and we read them
// as bf16, even-index ushorts are fp32 mantissa halves -> decode to huge
// values (>1e6 w.p. ~1 over 2048 samples). bf16 N(0,1) data maxes at ~4.
// flag: 0 = bf16, 1 = fp32
// ---------------------------------------------------------------------------
__global__ void detect_kernel(const ushort_t* __restrict__ x, int* __restrict__ flag) {
    __shared__ float red[256];
    int tid = threadIdx.x;
    float m = 0.f;
    for (int i = tid; i < 4096; i += 256) {
        float v = fabsf(bf2f(x[i]));
        m = fmaxf(m, v);   // fmaxf is NaN-ignoring (returns non-NaN operand)
    }
    red[tid] = m;
    __syncthreads();
    for (int s = 128; s > 0; s >>= 1) {
        if (tid < s) red[tid] = fmaxf(red[tid], red[tid + s]);
        __syncthreads();
    }
    if (tid == 0) *flag = (red[0] > 1e6f) ? 1 : 0;
}

// ---------------------------------------------------------------------------
// P0: effective attention weights: weff[h][k] = 0.125 * sum_d wa[d]*W[h*64+d][k]
//     beff[h] = 0.125 * sum_d wa[d]*b[h*64+d]
// ---------------------------------------------------------------------------
__global__ void eff_w_kernel(const void* __restrict__ W,   // 512x256
                             const void* __restrict__ b,   // 512
                             const void* __restrict__ wa,  // 64
                             float* __restrict__ weff,     // 8x256
                             float* __restrict__ beff,     // 8
                             const int* __restrict__ flag) {
    bool fp32 = (*flag != 0);
    __shared__ float was[64];
    int k = threadIdx.x;
    if (k < 64) was[k] = ldf(wa, k, fp32);
    __syncthreads();
    for (int h = 0; h < 8; h++) {
        float s = 0.f;
        for (int d = 0; d < 64; d++)
            s += was[d] * ldf(W, (long)(h * 64 + d) * KIN + k, fp32);
        weff[h * KIN + k] = 0.125f * s;
    }
    if (k < 8) {
        float s = 0.f;
        for (int d = 0; d < 64; d++) s += was[d] * ldf(b, k * 64 + d, fp32);
        beff[k] = 0.125f * s;
    }
}

// ---------------------------------------------------------------------------
// P1: per-node attention scalars aq[n][h], ak[n][h] (pre-scaled by 1/8)
// block 256 = 4 waves, one node per wave. grid = N/4
// ---------------------------------------------------------------------------
__global__ void attn_scalar_kernel(const void* __restrict__ X,     // N x 256
                                   const float* __restrict__ weff, // 16 x 256 (q:0-7, k:8-15)
                                   const float* __restrict__ beff, // 16
                                   float* __restrict__ aq,         // N x 8
                                   float* __restrict__ ak,         // N x 8
                                   const int* __restrict__ flag) {
    __shared__ float wl[16 * KIN];
    int tid = threadIdx.x;
    for (int i = tid; i < 16 * KIN; i += 256) wl[i] = weff[i];
    bool fp32 = (*flag != 0);
    __syncthreads();
    int lane = tid & 63, w = tid >> 6;
    int n = blockIdx.x * 4 + w;
    float xv0, xv1, xv2, xv3;
    if (fp32) {
        const float* xr = (const float*)X + (size_t)n * KIN + lane * 4;
        float4 u = *(const float4*)xr;
        xv0 = u.x; xv1 = u.y; xv2 = u.z; xv3 = u.w;
    } else {
        const ushort_t* xr = (const ushort_t*)X + (size_t)n * KIN + lane * 4;
        uint2 u = *(const uint2*)xr;
        xv0 = bf2f(u.x & 0xffff); xv1 = bf2f(u.x >> 16);
        xv2 = bf2f(u.y & 0xffff); xv3 = bf2f(u.y >> 16);
    }
    float p[16];
#pragma unroll
    for (int o = 0; o < 16; o++) {
        float4 wv = *(const float4*)&wl[o * KIN + lane * 4];
        p[o] = xv0 * wv.x + xv1 * wv.y + xv2 * wv.z + xv3 * wv.w;
    }
#pragma unroll
    for (int o = 0; o < 16; o++) {
        float v = p[o];
#pragma unroll
        for (int m = 32; m > 0; m >>= 1) v += __shfl_xor(v, m);
        if (lane == o) {
            float r = v + beff[o];
            if (o < 8) aq[n * 8 + o] = r;
            else       ak[n * 8 + (o - 8)] = r;
        }
    }
}

// ---------------------------------------------------------------------------
// P2: v projection GEMM. C[m][n] = sum_k A[m][k]*BT[n][k] + bias[n]
// A: M x 256, BT: 512 x 256 (Wv row-major), C: M x 512 bf16 (ws)
// 128x128 block tile, 4 waves 2x2, BK=64, mfma 16x16x32 bf16.
// bf16 input: async global_load_lds width-16. fp32 input: float4 -> f2bf -> ds_write.
// grid = (4, ceil(M/128)), block = 256
// ---------------------------------------------------------------------------
__global__ __launch_bounds__(256, 2) void gemm_v_kernel(
        const void* __restrict__ A, const void* __restrict__ BT,
        const void* __restrict__ bias, ushort_t* __restrict__ C, int M,
        const int* __restrict__ flag) {
    const int BK = 64;
    bool fp32 = (*flag != 0);
    int n0 = blockIdx.x * 128;
    int m0 = blockIdx.y * 128;
    int tid = threadIdx.x;
    int lane = tid & 63, w = tid >> 6;
    int wm = (w >> 1) * 64, wn = (w & 1) * 64;
    __shared__ ushort_t As[128 * BK];
    __shared__ ushort_t Bs[128 * BK];
    f32x4 acc[4][4] = {};

    for (int kt = 0; kt < KIN; kt += BK) {
        __syncthreads();
        if (!fp32) {
            const ushort_t* A16 = (const ushort_t*)A;
            const ushort_t* B16 = (const ushort_t*)BT;
#pragma unroll
            for (int i = 0; i < 4; i++) {
                int flat8 = i * 256 + tid;      // 8-elem chunk id, 0..1023
                int row = flat8 >> 3;           // 0..127
                int col = (flat8 & 7) * 8;
                int grow = m0 + row; if (grow > M - 1) grow = M - 1;  // clamp: full exec mask
                load_lds16(A16 + (size_t)grow * KIN + kt + col, &As[flat8 * 8]);
                load_lds16(B16 + (size_t)(n0 + row) * KIN + kt + col, &Bs[flat8 * 8]);
            }
        } else {
            const float* A32 = (const float*)A;
            const float* B32 = (const float*)BT;
#pragma unroll
            for (int i = 0; i < 8; i++) {
                int id = i * 256 + tid;         // 4-elem chunk id, 0..2047
                int row = id >> 4;              // 0..127
                int col = (id & 15) * 4;
                int grow = m0 + row; if (grow > M - 1) grow = M - 1;
                float4 va = *(const float4*)(A32 + (size_t)grow * KIN + kt + col);
                float4 vb = *(const float4*)(B32 + (size_t)(n0 + row) * KIN + kt + col);
                unsigned alo = (unsigned)f2bf(va.x) | ((unsigned)f2bf(va.y) << 16);
                unsigned ahi = (unsigned)f2bf(va.z) | ((unsigned)f2bf(va.w) << 16);
                unsigned blo = (unsigned)f2bf(vb.x) | ((unsigned)f2bf(vb.y) << 16);
                unsigned bhi = (unsigned)f2bf(vb.z) | ((unsigned)f2bf(vb.w) << 16);
                uint2 ua; ua.x = alo; ua.y = ahi;
                uint2 ub; ub.x = blo; ub.y = bhi;
                *(uint2*)&As[row * BK + col] = ua;
                *(uint2*)&Bs[row * BK + col] = ub;
            }
        }
        __syncthreads();
#pragma unroll
        for (int ks = 0; ks < BK; ks += 32) {
            short8 a[4], b[4];
#pragma unroll
            for (int i = 0; i < 4; i++)
                a[i] = *(const short8*)&As[(wm + i * 16 + (lane & 15)) * BK + ks + (lane >> 4) * 8];
#pragma unroll
            for (int j = 0; j < 4; j++)
                b[j] = *(const short8*)&Bs[(wn + j * 16 + (lane & 15)) * BK + ks + (lane >> 4) * 8];
#pragma unroll
            for (int i = 0; i < 4; i++)
#pragma unroll
                for (int j = 0; j < 4; j++)
                    acc[i][j] = __builtin_amdgcn_mfma_f32_16x16x32_bf16(a[i], b[j], acc[i][j], 0, 0, 0);
        }
    }
    int col_l = lane & 15, rq = lane >> 4;
#pragma unroll
    for (int i = 0; i < 4; i++) {
#pragma unroll
        for (int r = 0; r < 4; r++) {
            int row = m0 + wm + i * 16 + rq * 4 + r;
            if (row < M) {
#pragma unroll
                for (int j = 0; j < 4; j++) {
                    int cc = n0 + wn + j * 16 + col_l;
                    float bv = fp32 ? ((const float*)bias)[cc] : bf2f(((const ushort_t*)bias)[cc]);
                    C[(size_t)row * HDIM + cc] = f2bf(acc[i][j][r] + bv);
                }
            }
        }
    }
}

// ---------------------------------------------------------------------------
// E1: per-edge exp weights + denominator + degree (scores tiny: no max-shift
// needed, softmax ratio is shift-invariant). thread per edge.
// ---------------------------------------------------------------------------
__global__ void edge_pass1_kernel(const int* __restrict__ src, const int* __restrict__ dst,
                                  const float* __restrict__ ak,   // src-ntype, N x 8
                                  const float* __restrict__ aq,   // dst-ntype, N x 8
                                  float* __restrict__ wbuf,       // E x 8
                                  float* __restrict__ den,        // Nd x 8 (zeroed)
                                  int* __restrict__ deg) {        // Nd (zeroed)
    int e = blockIdx.x * 256 + threadIdx.x;
    if (e >= NEDGE) return;
    int s = src[e], d = dst[e];
#pragma unroll
    for (int h = 0; h < 8; h++) {
        float sc = ak[s * 8 + h] + aq[d * 8 + h];
        float wv = __expf(sc);
        wbuf[e * 8 + h] = wv;
        atomicAdd(&den[d * 8 + h], wv);
    }
    atomicAdd(&deg[d], 1);
}

// ---------------------------------------------------------------------------
// Scan: exclusive prefix sum of deg -> offs, 3 edge types, one launch
// ---------------------------------------------------------------------------
__global__ void scan3_kernel(const int* __restrict__ deg0, const int* __restrict__ deg1,
                             const int* __restrict__ deg2, int* __restrict__ offs0,
                             int* __restrict__ offs1, int* __restrict__ offs2) {
    const int Nd = NUSER;
    const int* deg = blockIdx.x == 0 ? deg0 : (blockIdx.x == 1 ? deg1 : deg2);
    int* offs = blockIdx.x == 0 ? offs0 : (blockIdx.x == 1 ? offs1 : offs2);
    __shared__ int lds[1024];
    int tid = threadIdx.x;
    int chunk = (Nd + 1023) >> 10;
    int s = tid * chunk;
    int e = s + chunk; if (e > Nd) e = Nd;
    int local = 0;
    for (int i = s; i < e; i++) local += deg[i];
    lds[tid] = local;
    __syncthreads();
    for (int d = 1; d < 1024; d <<= 1) {
        int v = (tid >= d) ? lds[tid - d] : 0;
        __syncthreads();
        lds[tid] += v;
        __syncthreads();
    }
    int run = (tid > 0) ? lds[tid - 1] : 0;
    for (int i = s; i < e; i++) { offs[i] = run; run += deg[i]; }
}

// ---------------------------------------------------------------------------
// E2: scatter edge ids into dst-sorted order
// ---------------------------------------------------------------------------
__global__ void edge_scatter_kernel(const int* __restrict__ dst, const int* __restrict__ offs,
                                    int* __restrict__ cur, int* __restrict__ esort) {
    int e = blockIdx.x * 256 + threadIdx.x;
    if (e >= NEDGE) return;
    int d = dst[e];
    int p = offs[d] + atomicAdd(&cur[d], 1);
    esort[p] = e;
}

// ---------------------------------------------------------------------------
// E3 (item): out[dst][c] = (sum_e v[src[e]][c]*w[e][h]) / (den[dst][h]*deg)
// grid = Nd*2 blocks of 256; block b -> dst = b>>1, c = (b&1)*256 + tid
// ---------------------------------------------------------------------------
__global__ void agg_item_kernel(const int* __restrict__ src, const int* __restrict__ esort,
                                const int* __restrict__ offs, const int* __restrict__ deg,
                                const float* __restrict__ den, const float* __restrict__ wbuf,
                                const ushort_t* __restrict__ V, void* __restrict__ outv,
                                const int* __restrict__ flag) {
    int d = blockIdx.x >> 1;
    int c = ((blockIdx.x & 1) << 8) + threadIdx.x;
    int h = c >> 6;
    int dg = deg[d];
    int o0 = offs[d];
    float acc = 0.f;
    for (int k = 0; k < dg; k++) {
        int e = esort[o0 + k];
        acc += bf2f(V[(size_t)src[e] * HDIM + c]) * wbuf[e * 8 + h];
    }
    float inv = dg > 0 ? 1.0f / (den[d * 8 + h] * (float)dg) : 0.f;
    float r = acc * inv;
    size_t idx = (size_t)NUSER * HDIM + (size_t)d * HDIM + c;  // h_item after h_user
    if (*flag) ((float*)outv)[idx] = r;
    else       ((ushort_t*)outv)[idx] = f2bf(r);
}

// ---------------------------------------------------------------------------
// E3 (user): fuses clicked_by (v_i) + follows (v_u)
// ---------------------------------------------------------------------------
__global__ void agg_user_kernel(
        const int* __restrict__ src1, const int* __restrict__ es1, const int* __restrict__ offs1,
        const int* __restrict__ deg1, const float* __restrict__ den1, const float* __restrict__ w1,
        const ushort_t* __restrict__ V1,
        const int* __restrict__ src2, const int* __restrict__ es2, const int* __restrict__ offs2,
        const int* __restrict__ deg2, const float* __restrict__ den2, const float* __restrict__ w2,
        const ushort_t* __restrict__ V2,
        void* __restrict__ outv, const int* __restrict__ flag) {
    int d = blockIdx.x >> 1;
    int c = ((blockIdx.x & 1) << 8) + threadIdx.x;
    int h = c >> 6;

    int dg1 = deg1[d], o1 = offs1[d];
    float acc1 = 0.f;
    for (int k = 0; k < dg1; k++) {
        int e = es1[o1 + k];
        acc1 += bf2f(V1[(size_t)src1[e] * HDIM + c]) * w1[e * 8 + h];
    }
    float inv1 = dg1 > 0 ? 1.0f / (den1[d * 8 + h] * (float)dg1) : 0.f;

    int dg2 = deg2[d], o2 = offs2[d];
    float acc2 = 0.f;
    for (int k = 0; k < dg2; k++) {
        int e = es2[o2 + k];
        acc2 += bf2f(V2[(size_t)src2[e] * HDIM + c]) * w2[e * 8 + h];
    }
    float inv2 = dg2 > 0 ? 1.0f / (den2[d * 8 + h] * (float)dg2) : 0.f;

    float r = acc1 * inv1 + acc2 * inv2;
    size_t idx = (size_t)d * HDIM + c;
    if (*flag) ((float*)outv)[idx] = r;
    else       ((ushort_t*)outv)[idx] = f2bf(r);
}

// ---------------------------------------------------------------------------
// kernel_launch
// ---------------------------------------------------------------------------
extern "C" void kernel_launch(void* const* d_in, const int* in_sizes, int n_in,
                              void* d_out, int out_size, void* d_ws, size_t ws_size,
                              hipStream_t stream) {
    const void* x_user  = d_in[0];
    const void* x_item  = d_in[1];
    const void* Wq_user = d_in[2];
    const void* bq_user = d_in[3];
    const void* Wk_user = d_in[4];
    const void* bk_user = d_in[5];
    const void* Wv_user = d_in[6];
    const void* bv_user = d_in[7];
    const void* Wq_item = d_in[8];
    const void* bq_item = d_in[9];
    const void* Wk_item = d_in[10];
    const void* bk_item = d_in[11];
    const void* Wv_item = d_in[12];
    const void* bv_item = d_in[13];
    const void* wa_user = d_in[14];
    const void* wa_item = d_in[15];
    const int* src_clicks     = (const int*)d_in[16];
    const int* dst_clicks     = (const int*)d_in[17];
    const int* src_clicked_by = (const int*)d_in[18];
    const int* dst_clicked_by = (const int*)d_in[19];
    const int* src_follows    = (const int*)d_in[20];
    const int* dst_follows    = (const int*)d_in[21];

    // workspace layout (bytes)
    char* ws = (char*)d_ws;
    ushort_t* v_u  = (ushort_t*)(ws + 0);           // 51,200,000
    ushort_t* v_i  = (ushort_t*)(ws + 51200000);    // 51,200,000
    float* aq_u    = (float*)(ws + 102400000);      // 1,600,000 each
    float* ak_u    = (float*)(ws + 104000000);
    float* aq_i    = (float*)(ws + 105600000);
    float* ak_i    = (float*)(ws + 107200000);
    float* weff_u  = (float*)(ws + 108800000);      // 16 KB (q rows 0-7, k rows 8-15)
    float* weff_i  = (float*)(ws + 108816384);      // 16 KB
    float* beff_u  = (float*)(ws + 108832768);      // 64 B (16 floats)
    float* beff_i  = (float*)(ws + 108832832);      // 64 B
    int*   dflag   = (int*)(ws + 108832896);        // 64 B (dtype flag)
    const size_t Z = 108832960;                     // zero-init region start
    float* den0 = (float*)(ws + Z + 0);             // 1,600,000 each
    float* den1 = (float*)(ws + Z + 1600000);
    float* den2 = (float*)(ws + Z + 3200000);
    int* deg0   = (int*)(ws + Z + 4800000);         // 200,000 each
    int* deg1   = (int*)(ws + Z + 5000000);
    int* deg2   = (int*)(ws + Z + 5200000);
    int* cur0   = (int*)(ws + Z + 5400000);
    int* cur1   = (int*)(ws + Z + 5600000);
    int* cur2   = (int*)(ws + Z + 5800000);
    const size_t ZLEN = 6000000;
    int* offs0  = (int*)(ws + Z + 6000000);
    int* offs1  = (int*)(ws + Z + 6200000);
    int* offs2  = (int*)(ws + Z + 6400000);
    int* es0    = (int*)(ws + Z + 6600000);         // 400,000 each
    int* es1    = (int*)(ws + Z + 7000000);
    int* es2    = (int*)(ws + Z + 7400000);
    float* wb0  = (float*)(ws + Z + 7800000);       // 3,200,000 each
    float* wb1  = (float*)(ws + Z + 11000000);
    float* wb2  = (float*)(ws + Z + 14200000);
    if (ws_size < Z + 17400000) return;

    // D0: dtype detect (must run first; every kernel branches on dflag)
    detect_kernel<<<1, 256, 0, stream>>>((const ushort_t*)x_user, dflag);

    // zero-init atomic accumulators (den/deg/cur)
    hipMemsetAsync(ws + Z, 0, ZLEN, stream);

    // P0: effective weights (q in rows 0-7, k in rows 8-15 of weff)
    eff_w_kernel<<<1, 256, 0, stream>>>(Wq_user, bq_user, wa_user, weff_u,        beff_u,     dflag);
    eff_w_kernel<<<1, 256, 0, stream>>>(Wk_user, bk_user, wa_user, weff_u + 2048, beff_u + 8, dflag);
    eff_w_kernel<<<1, 256, 0, stream>>>(Wq_item, bq_item, wa_item, weff_i,        beff_i,     dflag);
    eff_w_kernel<<<1, 256, 0, stream>>>(Wk_item, bk_item, wa_item, weff_i + 2048, beff_i + 8, dflag);

    // P2: v projections (bf16 MFMA GEMM, dual-dtype staging)
    dim3 ggrid(4, (NUSER + 127) / 128);
    gemm_v_kernel<<<ggrid, 256, 0, stream>>>(x_user, Wv_user, bv_user, v_u, NUSER, dflag);
    gemm_v_kernel<<<ggrid, 256, 0, stream>>>(x_item, Wv_item, bv_item, v_i, NITEM, dflag);

    // P1: attention scalars
    attn_scalar_kernel<<<NUSER / 4, 256, 0, stream>>>(x_user, weff_u, beff_u, aq_u, ak_u, dflag);
    attn_scalar_kernel<<<NITEM / 4, 256, 0, stream>>>(x_item, weff_i, beff_i, aq_i, ak_i, dflag);

    // E1: per-edge exp + den/deg. etype0=clicks(dst=item), 1=clicked_by(dst=user), 2=follows(dst=user)
    int eblocks = (NEDGE + 255) / 256;
    edge_pass1_kernel<<<eblocks, 256, 0, stream>>>(src_clicks, dst_clicks, ak_u, aq_i, wb0, den0, deg0);
    edge_pass1_kernel<<<eblocks, 256, 0, stream>>>(src_clicked_by, dst_clicked_by, ak_i, aq_u, wb1, den1, deg1);
    edge_pass1_kernel<<<eblocks, 256, 0, stream>>>(src_follows, dst_follows, ak_u, aq_u, wb2, den2, deg2);

    // scan (all 3 etypes, one launch)
    scan3_kernel<<<3, 1024, 0, stream>>>(deg0, deg1, deg2, offs0, offs1, offs2);

    // E2: dst-sorted edge lists
    edge_scatter_kernel<<<eblocks, 256, 0, stream>>>(dst_clicks, offs0, cur0, es0);
    edge_scatter_kernel<<<eblocks, 256, 0, stream>>>(dst_clicked_by, offs1, cur1, es1);
    edge_scatter_kernel<<<eblocks, 256, 0, stream>>>(dst_follows, offs2, cur2, es2);

    // E3: aggregate. h_item from clicks (v_u); h_user = clicked_by (v_i) + follows (v_u)
    agg_item_kernel<<<NITEM * 2, 256, 0, stream>>>(src_clicks, es0, offs0, deg0, den0, wb0, v_u, d_out, dflag);
    agg_user_kernel<<<NUSER * 2, 256, 0, stream>>>(
        src_clicked_by, es1, offs1, deg1, den1, wb1, v_i,
        src_follows,    es2, offs2, deg2, den2, wb2, v_u,
        d_out, dflag);
}

// Round 3
// 1083.164 us; speedup vs baseline: 1.4721x; 1.4721x over previous
//
#include <hip/hip_runtime.h>

// ---------------------------------------------------------------------------
// Problem constants
// ---------------------------------------------------------------------------
#define NUSER 50000
#define NITEM 50000
#define NEDGE 100000
#define HDIM  512      // H*D
#define KIN   256      // input feature dim

typedef unsigned short ushort_t;
typedef __attribute__((ext_vector_type(8))) short short8;
typedef __attribute__((ext_vector_type(4))) float f32x4;

static __device__ __forceinline__ float bf2f(ushort_t u) {
    unsigned v = ((unsigned)u) << 16;
    float f;
    __builtin_memcpy(&f, &v, 4);
    return f;
}
static __device__ __forceinline__ ushort_t f2bf(float f) {
    unsigned u;
    __builtin_memcpy(&u, &f, 4);
    unsigned r = u + 0x7fffu + ((u >> 16) & 1u);  // RNE
    return (ushort_t)(r >> 16);
}
// runtime-dtype scalar load
static __device__ __forceinline__ float ldf(const void* p, long i, bool fp32) {
    return fp32 ? ((const float*)p)[i] : bf2f(((const ushort_t*)p)[i]);
}

#define GLOBAL_AS __attribute__((address_space(1)))
#define LDS_AS    __attribute__((address_space(3)))
static __device__ __forceinline__ void load_lds16(const void* g, void* l) {
    __builtin_amdgcn_global_load_lds((const GLOBAL_AS void*)g, (LDS_AS void*)l, 16, 0, 0);
}

// ---------------------------------------------------------------------------
// D0: runtime dtype detection (0 = bf16, 1 = fp32). fp32 read as bf16 gives
// huge decoded values w.p. ~1 over 4096 samples; bf16 N(0,1) maxes ~4.
// ---------------------------------------------------------------------------
__global__ void detect_kernel(const ushort_t* __restrict__ x, int* __restrict__ flag) {
    __shared__ float red[256];
    int tid = threadIdx.x;
    float m = 0.f;
    for (int i = tid; i < 4096; i += 256) m = fmaxf(m, fabsf(bf2f(x[i])));
    red[tid] = m;
    __syncthreads();
    for (int s = 128; s > 0; s >>= 1) {
        if (tid < s) red[tid] = fmaxf(red[tid], red[tid + s]);
        __syncthreads();
    }
    if (tid == 0) *flag = (red[0] > 1e6f) ? 1 : 0;
}

// ---------------------------------------------------------------------------
// P0: effective attention weights, one block per head (grid = 8).
// weff[h][k] = 0.125 * sum_d wa[d]*W[h*64+d][k];  beff[h] = 0.125 * wa.b[h]
// ---------------------------------------------------------------------------
__global__ void eff_w_kernel(const void* __restrict__ W,   // 512x256
                             const void* __restrict__ b,   // 512
                             const void* __restrict__ wa,  // 64
                             float* __restrict__ weff,     // 8x256
                             float* __restrict__ beff,     // 8
                             const int* __restrict__ flag) {
    bool fp32 = (*flag != 0);
    int h = blockIdx.x;      // 0..7
    int k = threadIdx.x;     // 0..255
    __shared__ float was[64];
    __shared__ float red[64];
    if (k < 64) was[k] = ldf(wa, k, fp32);
    __syncthreads();
    float s = 0.f;
#pragma unroll 8
    for (int d = 0; d < 64; d++)
        s += was[d] * ldf(W, (long)(h * 64 + d) * KIN + k, fp32);
    weff[h * KIN + k] = 0.125f * s;
    if (k < 64) red[k] = was[k] * ldf(b, h * 64 + k, fp32);
    __syncthreads();
    if (k == 0) {
        float t = 0.f;
        for (int d = 0; d < 64; d++) t += red[d];
        beff[h] = 0.125f * t;
    }
}

// ---------------------------------------------------------------------------
// P1: per-node attention scalars aq[n][h], ak[n][h] (pre-scaled by 1/8)
// block 256 = 4 waves, one node per wave. grid = N/4
// ---------------------------------------------------------------------------
__global__ void attn_scalar_kernel(const void* __restrict__ X,     // N x 256
                                   const float* __restrict__ weff, // 16 x 256 (q:0-7, k:8-15)
                                   const float* __restrict__ beff, // 16
                                   float* __restrict__ aq,         // N x 8
                                   float* __restrict__ ak,         // N x 8
                                   const int* __restrict__ flag) {
    __shared__ float wl[16 * KIN];
    int tid = threadIdx.x;
    for (int i = tid; i < 16 * KIN; i += 256) wl[i] = weff[i];
    bool fp32 = (*flag != 0);
    __syncthreads();
    int lane = tid & 63, w = tid >> 6;
    int n = blockIdx.x * 4 + w;
    float xv0, xv1, xv2, xv3;
    if (fp32) {
        const float* xr = (const float*)X + (size_t)n * KIN + lane * 4;
        float4 u = *(const float4*)xr;
        xv0 = u.x; xv1 = u.y; xv2 = u.z; xv3 = u.w;
    } else {
        const ushort_t* xr = (const ushort_t*)X + (size_t)n * KIN + lane * 4;
        uint2 u = *(const uint2*)xr;
        xv0 = bf2f(u.x & 0xffff); xv1 = bf2f(u.x >> 16);
        xv2 = bf2f(u.y & 0xffff); xv3 = bf2f(u.y >> 16);
    }
    float p[16];
#pragma unroll
    for (int o = 0; o < 16; o++) {
        float4 wv = *(const float4*)&wl[o * KIN + lane * 4];
        p[o] = xv0 * wv.x + xv1 * wv.y + xv2 * wv.z + xv3 * wv.w;
    }
#pragma unroll
    for (int o = 0; o < 16; o++) {
        float v = p[o];
#pragma unroll
        for (int m = 32; m > 0; m >>= 1) v += __shfl_xor(v, m);
        if (lane == o) {
            float r = v + beff[o];
            if (o < 8) aq[n * 8 + o] = r;
            else       ak[n * 8 + (o - 8)] = r;
        }
    }
}

// ---------------------------------------------------------------------------
// P2: v projection GEMM (dual-dtype staging, bf16 MFMA 16x16x32, 128x128 tile)
// ---------------------------------------------------------------------------
__global__ __launch_bounds__(256, 2) void gemm_v_kernel(
        const void* __restrict__ A, const void* __restrict__ BT,
        const void* __restrict__ bias, ushort_t* __restrict__ C, int M,
        const int* __restrict__ flag) {
    const int BK = 64;
    bool fp32 = (*flag != 0);
    int n0 = blockIdx.x * 128;
    int m0 = blockIdx.y * 128;
    int tid = threadIdx.x;
    int lane = tid & 63, w = tid >> 6;
    int wm = (w >> 1) * 64, wn = (w & 1) * 64;
    __shared__ ushort_t As[128 * BK];
    __shared__ ushort_t Bs[128 * BK];
    f32x4 acc[4][4] = {};

    for (int kt = 0; kt < KIN; kt += BK) {
        __syncthreads();
        if (!fp32) {
            const ushort_t* A16 = (const ushort_t*)A;
            const ushort_t* B16 = (const ushort_t*)BT;
#pragma unroll
            for (int i = 0; i < 4; i++) {
                int flat8 = i * 256 + tid;      // 8-elem chunk id, 0..1023
                int row = flat8 >> 3;           // 0..127
                int col = (flat8 & 7) * 8;
                int grow = m0 + row; if (grow > M - 1) grow = M - 1;  // clamp: full exec mask
                load_lds16(A16 + (size_t)grow * KIN + kt + col, &As[flat8 * 8]);
                load_lds16(B16 + (size_t)(n0 + row) * KIN + kt + col, &Bs[flat8 * 8]);
            }
        } else {
            const float* A32 = (const float*)A;
            const float* B32 = (const float*)BT;
#pragma unroll
            for (int i = 0; i < 8; i++) {
                int id = i * 256 + tid;         // 4-elem chunk id, 0..2047
                int row = id >> 4;              // 0..127
                int col = (id & 15) * 4;
                int grow = m0 + row; if (grow > M - 1) grow = M - 1;
                float4 va = *(const float4*)(A32 + (size_t)grow * KIN + kt + col);
                float4 vb = *(const float4*)(B32 + (size_t)(n0 + row) * KIN + kt + col);
                uint2 ua, ub;
                ua.x = (unsigned)f2bf(va.x) | ((unsigned)f2bf(va.y) << 16);
                ua.y = (unsigned)f2bf(va.z) | ((unsigned)f2bf(va.w) << 16);
                ub.x = (unsigned)f2bf(vb.x) | ((unsigned)f2bf(vb.y) << 16);
                ub.y = (unsigned)f2bf(vb.z) | ((unsigned)f2bf(vb.w) << 16);
                *(uint2*)&As[row * BK + col] = ua;
                *(uint2*)&Bs[row * BK + col] = ub;
            }
        }
        __syncthreads();
#pragma unroll
        for (int ks = 0; ks < BK; ks += 32) {
            short8 a[4], b[4];
#pragma unroll
            for (int i = 0; i < 4; i++)
                a[i] = *(const short8*)&As[(wm + i * 16 + (lane & 15)) * BK + ks + (lane >> 4) * 8];
#pragma unroll
            for (int j = 0; j < 4; j++)
                b[j] = *(const short8*)&Bs[(wn + j * 16 + (lane & 15)) * BK + ks + (lane >> 4) * 8];
#pragma unroll
            for (int i = 0; i < 4; i++)
#pragma unroll
                for (int j = 0; j < 4; j++)
                    acc[i][j] = __builtin_amdgcn_mfma_f32_16x16x32_bf16(a[i], b[j], acc[i][j], 0, 0, 0);
        }
    }
    int col_l = lane & 15, rq = lane >> 4;
#pragma unroll
    for (int i = 0; i < 4; i++) {
#pragma unroll
        for (int r = 0; r < 4; r++) {
            int row = m0 + wm + i * 16 + rq * 4 + r;
            if (row < M) {
#pragma unroll
                for (int j = 0; j < 4; j++) {
                    int cc = n0 + wn + j * 16 + col_l;
                    float bv = fp32 ? ((const float*)bias)[cc] : bf2f(((const ushort_t*)bias)[cc]);
                    C[(size_t)row * HDIM + cc] = f2bf(acc[i][j][r] + bv);
                }
            }
        }
    }
}

// ---------------------------------------------------------------------------
// E1: per-edge exp weights + denominator + degree
// ---------------------------------------------------------------------------
__global__ void edge_pass1_kernel(const int* __restrict__ src, const int* __restrict__ dst,
                                  const float* __restrict__ ak,   // src-ntype, N x 8
                                  const float* __restrict__ aq,   // dst-ntype, N x 8
                                  float* __restrict__ wbuf,       // E x 8
                                  float* __restrict__ den,        // Nd x 8 (zeroed)
                                  int* __restrict__ deg) {        // Nd (zeroed)
    int e = blockIdx.x * 256 + threadIdx.x;
    if (e >= NEDGE) return;
    int s = src[e], d = dst[e];
#pragma unroll
    for (int h = 0; h < 8; h++) {
        float sc = ak[s * 8 + h] + aq[d * 8 + h];
        float wv = __expf(sc);
        wbuf[e * 8 + h] = wv;
        atomicAdd(&den[d * 8 + h], wv);
    }
    atomicAdd(&deg[d], 1);
}

// ---------------------------------------------------------------------------
// Scan: exclusive prefix sum of deg -> offs, 3 edge types, one launch
// ---------------------------------------------------------------------------
__global__ void scan3_kernel(const int* __restrict__ deg0, const int* __restrict__ deg1,
                             const int* __restrict__ deg2, int* __restrict__ offs0,
                             int* __restrict__ offs1, int* __restrict__ offs2) {
    const int Nd = NUSER;
    const int* deg = blockIdx.x == 0 ? deg0 : (blockIdx.x == 1 ? deg1 : deg2);
    int* offs = blockIdx.x == 0 ? offs0 : (blockIdx.x == 1 ? offs1 : offs2);
    __shared__ int lds[1024];
    int tid = threadIdx.x;
    int chunk = (Nd + 1023) >> 10;
    int s = tid * chunk;
    int e = s + chunk; if (e > Nd) e = Nd;
    int local = 0;
    for (int i = s; i < e; i++) local += deg[i];
    lds[tid] = local;
    __syncthreads();
    for (int d = 1; d < 1024; d <<= 1) {
        int v = (tid >= d) ? lds[tid - d] : 0;
        __syncthreads();
        lds[tid] += v;
        __syncthreads();
    }
    int run = (tid > 0) ? lds[tid - 1] : 0;
    for (int i = s; i < e; i++) { offs[i] = run; run += deg[i]; }
}

// ---------------------------------------------------------------------------
// E2: scatter edge ids into dst-sorted order
// ---------------------------------------------------------------------------
__global__ void edge_scatter_kernel(const int* __restrict__ dst, const int* __restrict__ offs,
                                    int* __restrict__ cur, int* __restrict__ esort) {
    int e = blockIdx.x * 256 + threadIdx.x;
    if (e >= NEDGE) return;
    int d = dst[e];
    int p = offs[d] + atomicAdd(&cur[d], 1);
    esort[p] = e;
}

// ---------------------------------------------------------------------------
// E3 helper: one wave aggregates one dst row for one etype.
// lane owns 8 channels (16B V load); edge/src ids prefetched 64-wide and
// broadcast via shuffle. acc[8] per lane.
// ---------------------------------------------------------------------------
static __device__ __forceinline__ void wave_agg_etype(
        int d, int lane, int hh,
        const int* __restrict__ src, const int* __restrict__ es,
        const int* __restrict__ offs, const int* __restrict__ deg,
        const float* __restrict__ den, const float* __restrict__ wbuf,
        const ushort_t* __restrict__ V, float* acc /*[8]*/, int* dg_out) {
    int dg = deg[d];
    int o0 = offs[d];
    *dg_out = dg;
    for (int base = 0; base < dg; base += 64) {
        int idx = base + lane;
        int ci = idx < dg ? idx : dg - 1;
        int el = es[o0 + ci];     // coalesced 64-wide prefetch
        int sl = src[el];
        int kmax = dg - base; if (kmax > 64) kmax = 64;
        for (int k = 0; k < kmax; k++) {
            int e = __shfl(el, k);
            int s = __shfl(sl, k);
            float wv = wbuf[e * 8 + hh];
            uint4 vv = *(const uint4*)(V + (size_t)s * HDIM + lane * 8);
            acc[0] += bf2f(vv.x & 0xffff) * wv;
            acc[1] += bf2f(vv.x >> 16) * wv;
            acc[2] += bf2f(vv.y & 0xffff) * wv;
            acc[3] += bf2f(vv.y >> 16) * wv;
            acc[4] += bf2f(vv.z & 0xffff) * wv;
            acc[5] += bf2f(vv.z >> 16) * wv;
            acc[6] += bf2f(vv.w & 0xffff) * wv;
            acc[7] += bf2f(vv.w >> 16) * wv;
        }
    }
}

// E3 (item): one wave per dst; block = 4 waves; grid = NITEM/4
__global__ void agg_item_kernel(const int* __restrict__ src, const int* __restrict__ esort,
                                const int* __restrict__ offs, const int* __restrict__ deg,
                                const float* __restrict__ den, const float* __restrict__ wbuf,
                                const ushort_t* __restrict__ V, void* __restrict__ outv,
                                const int* __restrict__ flag) {
    int lane = threadIdx.x & 63;
    int d = blockIdx.x * 4 + (threadIdx.x >> 6);
    int hh = lane >> 3;
    float acc[8] = {};
    int dg;
    wave_agg_etype(d, lane, hh, src, esort, offs, deg, den, wbuf, V, acc, &dg);
    float inv = dg > 0 ? 1.0f / (den[d * 8 + hh] * (float)dg) : 0.f;
    size_t base = (size_t)NUSER * HDIM + (size_t)d * HDIM + lane * 8;  // h_item after h_user
    if (*flag) {
        float* o = (float*)outv + base;
#pragma unroll
        for (int j = 0; j < 8; j++) o[j] = acc[j] * inv;
    } else {
        uint4 o;
        o.x = (unsigned)f2bf(acc[0] * inv) | ((unsigned)f2bf(acc[1] * inv) << 16);
        o.y = (unsigned)f2bf(acc[2] * inv) | ((unsigned)f2bf(acc[3] * inv) << 16);
        o.z = (unsigned)f2bf(acc[4] * inv) | ((unsigned)f2bf(acc[5] * inv) << 16);
        o.w = (unsigned)f2bf(acc[6] * inv) | ((unsigned)f2bf(acc[7] * inv) << 16);
        *(uint4*)((ushort_t*)outv + base) = o;
    }
}

// E3 (user): fuses clicked_by (v_i) + follows (v_u); one wave per dst
__global__ void agg_user_kernel(
        const int* __restrict__ src1, const int* __restrict__ es1, const int* __restrict__ offs1,
        const int* __restrict__ deg1, const float* __restrict__ den1, const float* __restrict__ w1,
        const ushort_t* __restrict__ V1,
        const int* __restrict__ src2, const int* __restrict__ es2, const int* __restrict__ offs2,
        const int* __restrict__ deg2, const float* __restrict__ den2, const float* __restrict__ w2,
        const ushort_t* __restrict__ V2,
        void* __restrict__ outv, const int* __restrict__ flag) {
    int lane = threadIdx.x & 63;
    int d = blockIdx.x * 4 + (threadIdx.x >> 6);
    int hh = lane >> 3;
    float acc1[8] = {}, acc2[8] = {};
    int dg1, dg2;
    wave_agg_etype(d, lane, hh, src1, es1, offs1, deg1, den1, w1, V1, acc1, &dg1);
    wave_agg_etype(d, lane, hh, src2, es2, offs2, deg2, den2, w2, V2, acc2, &dg2);
    float inv1 = dg1 > 0 ? 1.0f / (den1[d * 8 + hh] * (float)dg1) : 0.f;
    float inv2 = dg2 > 0 ? 1.0f / (den2[d * 8 + hh] * (float)dg2) : 0.f;
    float r[8];
#pragma unroll
    for (int j = 0; j < 8; j++) r[j] = acc1[j] * inv1 + acc2[j] * inv2;
    size_t base = (size_t)d * HDIM + lane * 8;
    if (*flag) {
        float* o = (float*)outv + base;
#pragma unroll
        for (int j = 0; j < 8; j++) o[j] = r[j];
    } else {
        uint4 o;
        o.x = (unsigned)f2bf(r[0]) | ((unsigned)f2bf(r[1]) << 16);
        o.y = (unsigned)f2bf(r[2]) | ((unsigned)f2bf(r[3]) << 16);
        o.z = (unsigned)f2bf(r[4]) | ((unsigned)f2bf(r[5]) << 16);
        o.w = (unsigned)f2bf(r[6]) | ((unsigned)f2bf(r[7]) << 16);
        *(uint4*)((ushort_t*)outv + base) = o;
    }
}

// ---------------------------------------------------------------------------
// kernel_launch
// ---------------------------------------------------------------------------
extern "C" void kernel_launch(void* const* d_in, const int* in_sizes, int n_in,
                              void* d_out, int out_size, void* d_ws, size_t ws_size,
                              hipStream_t stream) {
    const void* x_user  = d_in[0];
    const void* x_item  = d_in[1];
    const void* Wq_user = d_in[2];
    const void* bq_user = d_in[3];
    const void* Wk_user = d_in[4];
    const void* bk_user = d_in[5];
    const void* Wv_user = d_in[6];
    const void* bv_user = d_in[7];
    const void* Wq_item = d_in[8];
    const void* bq_item = d_in[9];
    const void* Wk_item = d_in[10];
    const void* bk_item = d_in[11];
    const void* Wv_item = d_in[12];
    const void* bv_item = d_in[13];
    const void* wa_user = d_in[14];
    const void* wa_item = d_in[15];
    const int* src_clicks     = (const int*)d_in[16];
    const int* dst_clicks     = (const int*)d_in[17];
    const int* src_clicked_by = (const int*)d_in[18];
    const int* dst_clicked_by = (const int*)d_in[19];
    const int* src_follows    = (const int*)d_in[20];
    const int* dst_follows    = (const int*)d_in[21];

    // workspace layout (bytes)
    char* ws = (char*)d_ws;
    ushort_t* v_u  = (ushort_t*)(ws + 0);           // 51,200,000
    ushort_t* v_i  = (ushort_t*)(ws + 51200000);    // 51,200,000
    float* aq_u    = (float*)(ws + 102400000);      // 1,600,000 each
    float* ak_u    = (float*)(ws + 104000000);
    float* aq_i    = (float*)(ws + 105600000);
    float* ak_i    = (float*)(ws + 107200000);
    float* weff_u  = (float*)(ws + 108800000);      // 16 KB (q rows 0-7, k rows 8-15)
    float* weff_i  = (float*)(ws + 108816384);      // 16 KB
    float* beff_u  = (float*)(ws + 108832768);      // 64 B (16 floats)
    float* beff_i  = (float*)(ws + 108832832);      // 64 B
    int*   dflag   = (int*)(ws + 108832896);        // 64 B (dtype flag)
    const size_t Z = 108832960;                     // zero-init region start
    float* den0 = (float*)(ws + Z + 0);             // 1,600,000 each
    float* den1 = (float*)(ws + Z + 1600000);
    float* den2 = (float*)(ws + Z + 3200000);
    int* deg0   = (int*)(ws + Z + 4800000);         // 200,000 each
    int* deg1   = (int*)(ws + Z + 5000000);
    int* deg2   = (int*)(ws + Z + 5200000);
    int* cur0   = (int*)(ws + Z + 5400000);
    int* cur1   = (int*)(ws + Z + 5600000);
    int* cur2   = (int*)(ws + Z + 5800000);
    const size_t ZLEN = 6000000;
    int* offs0  = (int*)(ws + Z + 6000000);
    int* offs1  = (int*)(ws + Z + 6200000);
    int* offs2  = (int*)(ws + Z + 6400000);
    int* es0    = (int*)(ws + Z + 6600000);         // 400,000 each
    int* es1    = (int*)(ws + Z + 7000000);
    int* es2    = (int*)(ws + Z + 7400000);
    float* wb0  = (float*)(ws + Z + 7800000);       // 3,200,000 each
    float* wb1  = (float*)(ws + Z + 11000000);
    float* wb2  = (float*)(ws + Z + 14200000);
    if (ws_size < Z + 17400000) return;

    // D0: dtype detect (must run first; consumers branch on dflag)
    detect_kernel<<<1, 256, 0, stream>>>((const ushort_t*)x_user, dflag);

    // zero-init atomic accumulators (den/deg/cur)
    hipMemsetAsync(ws + Z, 0, ZLEN, stream);

    // P0: effective weights (q in rows 0-7, k in rows 8-15 of weff); 8 blocks each
    eff_w_kernel<<<8, 256, 0, stream>>>(Wq_user, bq_user, wa_user, weff_u,        beff_u,     dflag);
    eff_w_kernel<<<8, 256, 0, stream>>>(Wk_user, bk_user, wa_user, weff_u + 2048, beff_u + 8, dflag);
    eff_w_kernel<<<8, 256, 0, stream>>>(Wq_item, bq_item, wa_item, weff_i,        beff_i,     dflag);
    eff_w_kernel<<<8, 256, 0, stream>>>(Wk_item, bk_item, wa_item, weff_i + 2048, beff_i + 8, dflag);

    // P2: v projections (bf16 MFMA GEMM, dual-dtype staging)
    dim3 ggrid(4, (NUSER + 127) / 128);
    gemm_v_kernel<<<ggrid, 256, 0, stream>>>(x_user, Wv_user, bv_user, v_u, NUSER, dflag);
    gemm_v_kernel<<<ggrid, 256, 0, stream>>>(x_item, Wv_item, bv_item, v_i, NITEM, dflag);

    // P1: attention scalars
    attn_scalar_kernel<<<NUSER / 4, 256, 0, stream>>>(x_user, weff_u, beff_u, aq_u, ak_u, dflag);
    attn_scalar_kernel<<<NITEM / 4, 256, 0, stream>>>(x_item, weff_i, beff_i, aq_i, ak_i, dflag);

    // E1: per-edge exp + den/deg. etype0=clicks(dst=item), 1=clicked_by(dst=user), 2=follows(dst=user)
    int eblocks = (NEDGE + 255) / 256;
    edge_pass1_kernel<<<eblocks, 256, 0, stream>>>(src_clicks, dst_clicks, ak_u, aq_i, wb0, den0, deg0);
    edge_pass1_kernel<<<eblocks, 256, 0, stream>>>(src_clicked_by, dst_clicked_by, ak_i, aq_u, wb1, den1, deg1);
    edge_pass1_kernel<<<eblocks, 256, 0, stream>>>(src_follows, dst_follows, ak_u, aq_u, wb2, den2, deg2);

    // scan (all 3 etypes, one launch)
    scan3_kernel<<<3, 1024, 0, stream>>>(deg0, deg1, deg2, offs0, offs1, offs2);

    // E2: dst-sorted edge lists
    edge_scatter_kernel<<<eblocks, 256, 0, stream>>>(dst_clicks, offs0, cur0, es0);
    edge_scatter_kernel<<<eblocks, 256, 0, stream>>>(dst_clicked_by, offs1, cur1, es1);
    edge_scatter_kernel<<<eblocks, 256, 0, stream>>>(dst_follows, offs2, cur2, es2);

    // E3: aggregate. h_item from clicks (v_u); h_user = clicked_by (v_i) + follows (v_u)
    agg_item_kernel<<<NITEM / 4, 256, 0, stream>>>(src_clicks, es0, offs0, deg0, den0, wb0, v_u, d_out, dflag);
    agg_user_kernel<<<NUSER / 4, 256, 0, stream>>>(
        src_clicked_by, es1, offs1, deg1, den1, wb1, v_i,
        src_follows,    es2, offs2, deg2, den2, wb2, v_u,
        d_out, dflag);
}